// Round 2
// baseline (109.108 us; speedup 1.0000x reference)
//
#include <hip/hip_runtime.h>
#include <hip/hip_fp16.h>
#include <cstdint>

// Problem constants
#define B_TOT  65536
#define D_TOT  256
#define H_SUB  16

// Per-feature piecewise-linear LUT over x in [-8, 8], 256 cells
#define TBL_N      256
#define TBL_XMIN   (-8.0f)
#define TBL_DELTA  0.0625f
#define INV_DELTA  16.0f
#define T_OFF      128.0f     // -TBL_XMIN * INV_DELTA

// Main-kernel tiling
#define DG      32                 // features per group
#define NG      (D_TOT / DG)       // 8 groups
#define RPB     512                // rows per block
#define NTH     256

__device__ __forceinline__ float tanh_fast(float z) {
    float e = __builtin_amdgcn_exp2f(z * 2.8853900817779268f);
    return 1.0f - 2.0f * __builtin_amdgcn_rcpf(e + 1.0f);
}

// ---------------------------------------------------------------------------
// Kernel 1: build LUTs (entry = half2(value, delta-to-next)) AND zero d_out.
// Grid is exactly D_TOT*TBL_N = 65536 = B_TOT threads, so out-zeroing folds in.
// ---------------------------------------------------------------------------
__global__ void build_tables(const float* __restrict__ w1,
                             const float* __restrict__ b1,
                             const float* __restrict__ w2,
                             const float* __restrict__ b2,
                             uint32_t* __restrict__ tab,
                             float* __restrict__ out) {
    int gid = blockIdx.x * NTH + threadIdx.x;      // 0 .. 65535
    out[gid] = 0.0f;                               // B_TOT == D_TOT*TBL_N
    int d = gid >> 8;                              // TBL_N == 256
    int i = gid & (TBL_N - 1);
    float x0 = TBL_XMIN + (float)i * TBL_DELTA;
    float x1 = x0 + TBL_DELTA;
    float f0 = 0.0f, f1 = 0.0f;
#pragma unroll
    for (int h = 0; h < H_SUB; ++h) {
        float a = w1[d * H_SUB + h];
        float c = b1[d * H_SUB + h];
        float w = w2[d * H_SUB + h];
        f0 += w * tanh_fast(fmaf(a, x0, c));
        f1 += w * tanh_fast(fmaf(a, x1, c));
    }
    float val = f0 + b2[d];
    float slp = f1 - f0;
    __half2 h2 = __halves2half2(__float2half_rn(val), __float2half_rn(slp));
    tab[gid] = *reinterpret_cast<uint32_t*>(&h2);
}

// ---------------------------------------------------------------------------
// Kernel 2: coalesced streaming gather.
// Block = (group g of 32 features, chunk of 512 rows). 32 KiB LDS table ->
// 4 blocks/CU. Lane ell = (subrow = ell>>3, featquad = ell&7): one
// global_load_dwordx4 covers 8 rows x 128B contiguous segments (all lines
// fully consumed, no L1 reuse needed). Row sum via 3 shfl_xor over the 8
// feature-quads; lane fq==0 does one atomicAdd per row per group.
// ---------------------------------------------------------------------------
__global__ __launch_bounds__(NTH, 4) void kan_forward(
        const float* __restrict__ x,
        const uint32_t* __restrict__ tab,
        float* __restrict__ out) {
    __shared__ uint32_t sT[DG * TBL_N];            // 32 KiB

    const int g  = blockIdx.x & (NG - 1);
    const int bc = blockIdx.x >> 3;                // NG == 8

    // Coalesced table fill: 8192 u32 = 2048 uint4, 8 per thread
    {
        const uint4* src = reinterpret_cast<const uint4*>(tab + g * DG * TBL_N);
        uint4* dst = reinterpret_cast<uint4*>(sT);
#pragma unroll
        for (int k = 0; k < (DG * TBL_N / 4) / NTH; ++k)
            dst[threadIdx.x + k * NTH] = src[threadIdx.x + k * NTH];
    }
    __syncthreads();

    const int lane   = threadIdx.x & 63;
    const int wave   = threadIdx.x >> 6;
    const int subrow = lane >> 3;                  // 0..7
    const int fq     = lane & 7;                   // feature quad 0..7

    const int row0 = bc * RPB + wave * 8 + subrow;
    const float* xb = x + (size_t)row0 * D_TOT + g * DG + fq * 4;

#pragma unroll 4
    for (int it = 0; it < RPB / 32; ++it) {        // 16 iters, 32 rows/block/iter
        const float4 xv =
            *reinterpret_cast<const float4*>(xb + (size_t)it * 32 * D_TOT);
        float xs[4] = {xv.x, xv.y, xv.z, xv.w};
        float acc = 0.0f;
#pragma unroll
        for (int c = 0; c < 4; ++c) {
            float t = fmaf(xs[c], INV_DELTA, T_OFF);
            t = fminf(fmaxf(t, 0.0f), 255.99f);
            float fi = floorf(t);
            float u = t - fi;
            uint32_t e = sT[(fq * 4 + c) * TBL_N + (int)fi];
            union { uint32_t u32; __half2 h2; } cv;
            cv.u32 = e;
            acc += fmaf(__high2float(cv.h2), u, __low2float(cv.h2));
        }
        // reduce the 8 feature-quads of this row (lanes differing in bits 0..2)
        acc += __shfl_xor(acc, 1);
        acc += __shfl_xor(acc, 2);
        acc += __shfl_xor(acc, 4);
        if (fq == 0)
            atomicAdd(&out[row0 + it * 32], acc);
    }
}

extern "C" void kernel_launch(void* const* d_in, const int* in_sizes, int n_in,
                              void* d_out, int out_size, void* d_ws, size_t ws_size,
                              hipStream_t stream) {
    const float* x  = (const float*)d_in[0];
    const float* w1 = (const float*)d_in[1];
    const float* b1 = (const float*)d_in[2];
    const float* w2 = (const float*)d_in[3];
    const float* b2 = (const float*)d_in[4];
    float* out = (float*)d_out;
    uint32_t* tab = (uint32_t*)d_ws;               // 256 KiB

    build_tables<<<dim3(D_TOT * TBL_N / NTH), dim3(NTH), 0, stream>>>(
        w1, b1, w2, b2, tab, out);

    kan_forward<<<dim3((B_TOT / RPB) * NG), dim3(NTH), 0, stream>>>(
        x, tab, out);
}